// Round 8
// baseline (283.522 us; speedup 1.0000x reference)
//
#include <hip/hip_runtime.h>
#include <hip/hip_bf16.h>
#include <cstdint>
#include <cstddef>

typedef __hip_bfloat16 bf16;
typedef short short8 __attribute__((ext_vector_type(8)));
typedef float f32x4 __attribute__((ext_vector_type(4)));

#define S_LEN 2048
#define DMODEL 2048
#define NQKV 6144
#define NHEADS 32
#define HDIM 64
// log2(10000)/32
#define ROPE_L2 0.4152410118609203f

__device__ __forceinline__ void async_copy16(const bf16* g, bf16* l) {
  __builtin_amdgcn_global_load_lds(
      (const __attribute__((address_space(1))) void*)g,
      (__attribute__((address_space(3))) void*)l, 16, 0, 0);
}

__device__ __forceinline__ f32x4 mfma_bf16(short8 a, short8 b, f32x4 c) {
  return __builtin_amdgcn_mfma_f32_16x16x32_bf16(a, b, c, 0, 0, 0);
}

// ---------------- fused fp32 -> bf16 convert of x, Wqkv, Wo ----------------
__global__ __launch_bounds__(256) void cvt3_kernel(const float* __restrict__ sx,
                                                   bf16* __restrict__ dx,
                                                   const float* __restrict__ sw,
                                                   bf16* __restrict__ dw,
                                                   const float* __restrict__ so,
                                                   bf16* __restrict__ dov) {
  int i = blockIdx.x * 256 + threadIdx.x;
  const float* s;
  bf16* d;
  if (i < 1048576) {
    s = sx; d = dx;
  } else if (i < 4194304) {
    s = sw; d = dw; i -= 1048576;
  } else {
    s = so; d = dov; i -= 4194304;
  }
  const float4 v = ((const float4*)s)[i];
  union { bf16 h[4]; ushort4 u; } tmp;
  tmp.h[0] = __float2bfloat16(v.x);
  tmp.h[1] = __float2bfloat16(v.y);
  tmp.h[2] = __float2bfloat16(v.z);
  tmp.h[3] = __float2bfloat16(v.w);
  ((ushort4*)d)[i] = tmp.u;
}

// ---------------- GEMM1: qkv = x @ Wqkv^T, fused RoPE epilogue ----------------
// BK=64 as two stacked proven BK=32 sub-tiles (A0/A1, W0/W1): half the barriers,
// 32 MFMA between barriers, identical (measured-clean) swizzle per sub-tile.
__global__ __launch_bounds__(256) void gemm_qkv(const bf16* __restrict__ A,
                                                const bf16* __restrict__ W,
                                                bf16* __restrict__ q_ws,
                                                bf16* __restrict__ k_ws,
                                                bf16* __restrict__ v_ws) {
  constexpr int K = DMODEL;
  __shared__ bf16 smem[16384];  // A0[0:4096] A1[4096:8192] W0[8192:12288] W1[12288:16384]
  const int tid = threadIdx.x;
  const int wave = tid >> 6, lane = tid & 63;
  const int wm = wave >> 1, wn = wave & 1;
  const int m0 = blockIdx.y * 128, n0 = blockIdx.x * 128;
  const int sr = wave * 16 + (lane >> 2);
  const int swc = (((lane & 3) ^ ((lane >> 3) & 3)) * 8);  // swizzled src chunk
  const int fr = lane & 15, fq = lane >> 4;
  const int rdc = ((fq ^ ((fr >> 1) & 3)) * 8);

  const f32x4 zero = {0.f, 0.f, 0.f, 0.f};
  f32x4 acc[4][4];
  for (int i = 0; i < 4; ++i)
    for (int j = 0; j < 4; ++j) acc[i][j] = zero;

  for (int kt = 0; kt < K; kt += 64) {
    __syncthreads();
    for (int i2 = 0; i2 < 2; ++i2) {
      const size_t ra = (size_t)(m0 + i2 * 64 + sr) * K + kt;
      const size_t rw = (size_t)(n0 + i2 * 64 + sr) * K + kt;
      const int db = (i2 * 64 + wave * 16) * 32;
      async_copy16(A + ra + swc,        &smem[db]);
      async_copy16(A + ra + 32 + swc,   &smem[4096 + db]);
      async_copy16(W + rw + swc,        &smem[8192 + db]);
      async_copy16(W + rw + 32 + swc,   &smem[12288 + db]);
    }
    __syncthreads();
#pragma unroll
    for (int kk = 0; kk < 2; ++kk) {
      const int ab = kk * 4096, wb = 8192 + kk * 4096;
      short8 a[4], b[4];
#pragma unroll
      for (int i = 0; i < 4; ++i)
        a[i] = *(const short8*)&smem[ab + (wm * 64 + i * 16 + fr) * 32 + rdc];
#pragma unroll
      for (int j = 0; j < 4; ++j)
        b[j] = *(const short8*)&smem[wb + (wn * 64 + j * 16 + fr) * 32 + rdc];
#pragma unroll
      for (int i = 0; i < 4; ++i)
#pragma unroll
        for (int j = 0; j < 4; ++j)
          acc[i][j] = mfma_bf16(a[i], b[j], acc[i][j]);
    }
  }

  const int colb = n0 + wn * 64;
  const int sect = colb >> 11;          // 0=q, 1=k, 2=v (block-uniform)
  const int h = (colb & 2047) >> 6;
  const int col = fr, rq = fq * 4;

  if (sect < 2) {
    bf16* dst = ((sect == 0) ? q_ws : k_ws) + (size_t)h * S_LEN * HDIM;
    bf16* rep = smem + wave * 1152;     // 16 rows x stride 72 (16B-aligned)
    const float f0 = exp2f(-(float)col * ROPE_L2);
    const float f1 = exp2f(-(float)(16 + col) * ROPE_L2);
    __syncthreads();
    for (int i = 0; i < 4; ++i) {
      const int base_s = m0 + wm * 64 + i * 16;
#pragma unroll
      for (int jl = 0; jl < 2; ++jl) {
        const int dh = jl * 16 + col;
        const float fr_ = (jl == 0) ? f0 : f1;
#pragma unroll
        for (int r = 0; r < 4; ++r) {
          const int srow = base_s + rq + r;
          float sn, cs;
          __sincosf((float)srow * fr_, &sn, &cs);
          const float xl = acc[i][jl][r], xh = acc[i][jl + 2][r];
          rep[(rq + r) * 72 + dh]      = __float2bfloat16(xl * cs - xh * sn);
          rep[(rq + r) * 72 + dh + 32] = __float2bfloat16(xh * cs + xl * sn);
        }
      }
#pragma unroll
      for (int p = 0; p < 2; ++p) {
        const int rr = p * 8 + (lane >> 3), ch = lane & 7;
        const uint4 vv = *(const uint4*)&rep[rr * 72 + ch * 8];
        *(uint4*)&dst[(size_t)(base_s + rr) * HDIM + ch * 8] = vv;
      }
    }
  } else {
    // V stored transposed: [h][dh][s]
    bf16* dst = v_ws + (size_t)h * HDIM * S_LEN;
    for (int j = 0; j < 4; ++j) {
      const int dh = j * 16 + col;
      for (int i = 0; i < 4; ++i) {
        const int s0 = m0 + wm * 64 + i * 16 + rq;
        union { bf16 hx[4]; uint2 u; } vk;
#pragma unroll
        for (int r = 0; r < 4; ++r) vk.hx[r] = __float2bfloat16(acc[i][j][r]);
        *(uint2*)&dst[(size_t)dh * S_LEN + s0] = vk.u;
      }
    }
  }
}

// ---------------- flash attention (causal), 32 q per wave ----------------
// 256-thr blocks (4 waves x 32 q = 128 q), grid 512 = 16 q-pairs (LPT
// heavy-first) x 32 heads. K/V staged once per 128 q, double-buffered, one
// barrier per k-tile (proven R5 geometry byte-for-byte). NO divergent loop
// bounds: all waves run the block-uniform tile count; causal mask is
// branch-free per q-group under a wave-uniform guard; fully-masked tiles are
// exact softmax no-ops (vmax=-1e30 -> alpha=1, p=0).
__global__ __launch_bounds__(256) void attn_kernel(const bf16* __restrict__ q_ws,
                                                   const bf16* __restrict__ k_ws,
                                                   const bf16* __restrict__ vt_ws,
                                                   bf16* __restrict__ attn_out) {
  const int bid = blockIdx.x;
  const int t = 15 - (bid >> 5);       // heavy q-pairs first (LPT)
  const int h = bid & 31;
  const int qb = t * 128;
  const int nkt = 2 * t + 2;           // tiles for this block (uniform)

  const int tid = threadIdx.x, wave = tid >> 6, lane = tid & 63;
  const int col = lane & 15, fq = lane >> 4;
  const int q0g = qb + wave * 32 + col;     // group-0 query
  const int q1g = q0g + 16;                 // group-1 query

  __shared__ bf16 Ks[2][64 * 64];
  __shared__ bf16 Vs[2][64 * 64];
  __shared__ bf16 Pl[4][32 * 72];
  bf16* pl = Pl[wave];

  const bf16* qh = q_ws + (size_t)h * S_LEN * HDIM;
  const bf16* kh = k_ws + (size_t)h * S_LEN * HDIM;
  const bf16* vh = vt_ws + (size_t)h * HDIM * S_LEN;

  const int srow = lane >> 3;
  const int slot = lane & 7;
  const int schunk = slot ^ srow;

  auto stage = [&](int kt, int buf) {
    const int k0 = kt * 64;
#pragma unroll
    for (int j = 0; j < 2; ++j) {
      const int r8 = (wave * 2 + j) * 8;
      async_copy16(kh + (size_t)(k0 + r8 + srow) * HDIM + schunk * 8,
                   &Ks[buf][r8 * 64]);
      async_copy16(vh + (size_t)(r8 + srow) * S_LEN + k0 + schunk * 8,
                   &Vs[buf][r8 * 64]);
    }
  };

  short8 qf[2][2];
#pragma unroll
  for (int g = 0; g < 2; ++g)
#pragma unroll
    for (int ks = 0; ks < 2; ++ks)
      qf[g][ks] =
          *(const short8*)&qh[(size_t)(q0g + g * 16) * HDIM + ks * 32 + fq * 8];

  const f32x4 zero = {0.f, 0.f, 0.f, 0.f};
  f32x4 o0[4] = {zero, zero, zero, zero};
  f32x4 o1[4] = {zero, zero, zero, zero};
  float m0v = -1e30f, l0v = 0.f, m1v = -1e30f, l1v = 0.f;

  stage(0, 0);

  for (int kt = 0; kt < nkt; ++kt) {
    const int buf = kt & 1;
    const int k0 = kt * 64;
    __syncthreads();
    if (kt + 1 < nkt) stage(kt + 1, buf ^ 1);

    short8 kf[8];
#pragma unroll
    for (int n = 0; n < 4; ++n) {
      const int row = n * 16 + col;
#pragma unroll
      for (int ks = 0; ks < 2; ++ks)
        kf[n * 2 + ks] =
            *(const short8*)&Ks[buf][row * 64 + (((ks * 4 + fq) ^ (row & 7)) * 8)];
    }
    f32x4 s0[4] = {zero, zero, zero, zero};
    f32x4 s1[4] = {zero, zero, zero, zero};
#pragma unroll
    for (int n = 0; n < 4; ++n)
#pragma unroll
      for (int ks = 0; ks < 2; ++ks) {
        s0[n] = mfma_bf16(kf[n * 2 + ks], qf[0][ks], s0[n]);
        s1[n] = mfma_bf16(kf[n * 2 + ks], qf[1][ks], s1[n]);
      }

    short8 vf[8];
#pragma unroll
    for (int n = 0; n < 4; ++n) {
      const int row = n * 16 + col;
#pragma unroll
      for (int ks = 0; ks < 2; ++ks)
        vf[n * 2 + ks] =
            *(const short8*)&Vs[buf][row * 64 + (((ks * 4 + fq) ^ (row & 7)) * 8)];
    }

    // causal mask per group (wave-uniform guard; branch-free inside)
    if (k0 + 63 > qb + wave * 32) {
#pragma unroll
      for (int n = 0; n < 4; ++n)
#pragma unroll
        for (int r = 0; r < 4; ++r)
          if (k0 + n * 16 + fq * 4 + r > q0g) s0[n][r] = -1e30f;
    }
    if (k0 + 63 > qb + wave * 32 + 16) {
#pragma unroll
      for (int n = 0; n < 4; ++n)
#pragma unroll
        for (int r = 0; r < 4; ++r)
          if (k0 + n * 16 + fq * 4 + r > q1g) s1[n][r] = -1e30f;
    }

    // ---- softmax group 0 ----
    {
      float vmax = -1e30f;
#pragma unroll
      for (int n = 0; n < 4; ++n)
#pragma unroll
        for (int r = 0; r < 4; ++r) vmax = fmaxf(vmax, s0[n][r]);
      vmax = fmaxf(vmax, __shfl_xor(vmax, 16, 64));
      vmax = fmaxf(vmax, __shfl_xor(vmax, 32, 64));
      const float mnew = fmaxf(m0v, vmax);
      const float alpha = __expf((m0v - mnew) * 0.125f);
      m0v = mnew;
      float rs = 0.f;
#pragma unroll
      for (int n = 0; n < 4; ++n)
#pragma unroll
        for (int r = 0; r < 4; ++r) {
          const float p = __expf((s0[n][r] - mnew) * 0.125f);
          s0[n][r] = p;
          rs += p;
        }
      rs += __shfl_xor(rs, 16, 64);
      rs += __shfl_xor(rs, 32, 64);
      l0v = l0v * alpha + rs;
#pragma unroll
      for (int n = 0; n < 4; ++n) {
#pragma unroll
        for (int r = 0; r < 4; ++r) o0[n][r] *= alpha;
        union { bf16 hx[4]; uint2 u; } pk;
#pragma unroll
        for (int r = 0; r < 4; ++r) pk.hx[r] = __float2bfloat16(s0[n][r]);
        *(uint2*)&pl[col * 72 + n * 16 + fq * 4] = pk.u;
      }
    }
    // ---- softmax group 1 ----
    {
      float vmax = -1e30f;
#pragma unroll
      for (int n = 0; n < 4; ++n)
#pragma unroll
        for (int r = 0; r < 4; ++r) vmax = fmaxf(vmax, s1[n][r]);
      vmax = fmaxf(vmax, __shfl_xor(vmax, 16, 64));
      vmax = fmaxf(vmax, __shfl_xor(vmax, 32, 64));
      const float mnew = fmaxf(m1v, vmax);
      const float alpha = __expf((m1v - mnew) * 0.125f);
      m1v = mnew;
      float rs = 0.f;
#pragma unroll
      for (int n = 0; n < 4; ++n)
#pragma unroll
        for (int r = 0; r < 4; ++r) {
          const float p = __expf((s1[n][r] - mnew) * 0.125f);
          s1[n][r] = p;
          rs += p;
        }
      rs += __shfl_xor(rs, 16, 64);
      rs += __shfl_xor(rs, 32, 64);
      l1v = l1v * alpha + rs;
#pragma unroll
      for (int n = 0; n < 4; ++n) {
#pragma unroll
        for (int r = 0; r < 4; ++r) o1[n][r] *= alpha;
        union { bf16 hx[4]; uint2 u; } pk;
#pragma unroll
        for (int r = 0; r < 4; ++r) pk.hx[r] = __float2bfloat16(s1[n][r]);
        *(uint2*)&pl[(16 + col) * 72 + n * 16 + fq * 4] = pk.u;
      }
    }

    short8 pa0[2], pa1[2];
#pragma unroll
    for (int ks = 0; ks < 2; ++ks) {
      pa0[ks] = *(const short8*)&pl[col * 72 + ks * 32 + fq * 8];
      pa1[ks] = *(const short8*)&pl[(16 + col) * 72 + ks * 32 + fq * 8];
    }
#pragma unroll
    for (int n = 0; n < 4; ++n)
#pragma unroll
      for (int ks = 0; ks < 2; ++ks) {
        o0[n] = mfma_bf16(vf[n * 2 + ks], pa0[ks], o0[n]);
        o1[n] = mfma_bf16(vf[n * 2 + ks], pa1[ks], o1[n]);
      }
  }

  const float inv0 = 1.0f / l0v, inv1 = 1.0f / l1v;
#pragma unroll
  for (int n = 0; n < 4; ++n) {
    union { bf16 hx[4]; uint2 u; } ok;
#pragma unroll
    for (int r = 0; r < 4; ++r) ok.hx[r] = __float2bfloat16(o0[n][r] * inv0);
    *(uint2*)&attn_out[(size_t)q0g * DMODEL + h * HDIM + n * 16 + fq * 4] = ok.u;
#pragma unroll
    for (int r = 0; r < 4; ++r) ok.hx[r] = __float2bfloat16(o1[n][r] * inv1);
    *(uint2*)&attn_out[(size_t)q1g * DMODEL + h * HDIM + n * 16 + fq * 4] = ok.u;
  }
}

// ---------------- GEMM2: out = attn @ Wo^T, fused residual+gate ----------------
// 64x128 tile, BK=64 (two stacked BK=32 sub-tiles), grid 512 = 2 blocks/CU.
__global__ __launch_bounds__(256) void gemm_out(const bf16* __restrict__ A,
                                                const bf16* __restrict__ W,
                                                const float* __restrict__ xres,
                                                const float* __restrict__ gate,
                                                float* __restrict__ out) {
  constexpr int K = DMODEL;
  __shared__ bf16 smem[12288];  // A0[0:2048] A1[2048:4096] W0[4096:8192] W1[8192:12288]
  const int tid = threadIdx.x;
  const int wave = tid >> 6, lane = tid & 63;
  const int m0 = blockIdx.y * 64, n0 = blockIdx.x * 128;
  const int sr = lane >> 2;
  const int swc = (((lane & 3) ^ ((lane >> 3) & 3)) * 8);
  const int fr = lane & 15, fq = lane >> 4;
  const int rdc = ((fq ^ ((fr >> 1) & 3)) * 8);

  const f32x4 zero = {0.f, 0.f, 0.f, 0.f};
  f32x4 acc[4][2];
  for (int i = 0; i < 4; ++i)
    for (int j = 0; j < 2; ++j) acc[i][j] = zero;

  for (int kt = 0; kt < K; kt += 64) {
    __syncthreads();
    {
      const size_t ra = (size_t)(m0 + wave * 16 + sr) * K + kt;
      async_copy16(A + ra + swc,      &smem[(wave * 16) * 32]);
      async_copy16(A + ra + 32 + swc, &smem[2048 + (wave * 16) * 32]);
#pragma unroll
      for (int j = 0; j < 2; ++j) {
        const size_t rw = (size_t)(n0 + wave * 32 + j * 16 + sr) * K + kt;
        const int db = (wave * 32 + j * 16) * 32;
        async_copy16(W + rw + swc,      &smem[4096 + db]);
        async_copy16(W + rw + 32 + swc, &smem[8192 + db]);
      }
    }
    __syncthreads();
#pragma unroll
    for (int kk = 0; kk < 2; ++kk) {
      const int ab = kk * 2048, wb = 4096 + kk * 4096;
      short8 a[4], b[2];
#pragma unroll
      for (int i = 0; i < 4; ++i)
        a[i] = *(const short8*)&smem[ab + (i * 16 + fr) * 32 + rdc];
#pragma unroll
      for (int j = 0; j < 2; ++j)
        b[j] = *(const short8*)&smem[wb + (wave * 32 + j * 16 + fr) * 32 + rdc];
#pragma unroll
      for (int i = 0; i < 4; ++i)
#pragma unroll
        for (int j = 0; j < 2; ++j)
          acc[i][j] = mfma_bf16(a[i], b[j], acc[i][j]);
    }
  }

  const int col = fr, rq = fq * 4;
  for (int j = 0; j < 2; ++j) {
    const int cc = n0 + wave * 32 + j * 16 + col;
    const float g = gate[cc];
    for (int i = 0; i < 4; ++i) {
      const int base_row = m0 + i * 16 + rq;
      for (int r = 0; r < 4; ++r) {
        const size_t idx = (size_t)(base_row + r) * DMODEL + cc;
        out[idx] = xres[idx] + g * acc[i][j][r];
      }
    }
  }
}

extern "C" void kernel_launch(void* const* d_in, const int* in_sizes, int n_in,
                              void* d_out, int out_size, void* d_ws, size_t ws_size,
                              hipStream_t stream) {
  const float* x    = (const float*)d_in[0];
  const float* Wqkv = (const float*)d_in[1];
  const float* Wo   = (const float*)d_in[2];
  const float* gate = (const float*)d_in[3];
  float* out = (float*)d_out;

  char* ws = (char*)d_ws;
  const size_t MB = 1024 * 1024;
  bf16* xb      = (bf16*)(ws);                 // 8 MB   (dead after gemm_qkv)
  bf16* wqkvb   = (bf16*)(ws + 8 * MB);        // 24 MB  (dead after gemm_qkv)
  bf16* wob     = (bf16*)(ws + 32 * MB);       // 8 MB
  bf16* q_ws    = (bf16*)(ws + 40 * MB);       // 8 MB  [h][s][dh]
  bf16* k_ws    = (bf16*)(ws + 48 * MB);       // 8 MB  [h][s][dh]
  bf16* v_ws    = (bf16*)(ws + 56 * MB);       // 8 MB  [h][dh][s] (pre-transposed)
  bf16* attn_ws = (bf16*)(ws);                 // aliases xb

  cvt3_kernel<<<dim3(20480), 256, 0, stream>>>(x, xb, Wqkv, wqkvb, Wo, wob);

  gemm_qkv<<<dim3(NQKV / 128, DMODEL / 128), 256, 0, stream>>>(xb, wqkvb, q_ws, k_ws, v_ws);
  attn_kernel<<<dim3(512), 256, 0, stream>>>(q_ws, k_ws, v_ws, attn_ws);
  gemm_out<<<dim3(DMODEL / 128, DMODEL / 64), 256, 0, stream>>>(attn_ws, wob, x, gate, out);
}

// Round 9
// 256.686 us; speedup vs baseline: 1.1045x; 1.1045x over previous
//
#include <hip/hip_runtime.h>
#include <hip/hip_bf16.h>
#include <cstdint>
#include <cstddef>

typedef __hip_bfloat16 bf16;
typedef short short8 __attribute__((ext_vector_type(8)));
typedef float f32x4 __attribute__((ext_vector_type(4)));

#define S_LEN 2048
#define DMODEL 2048
#define NQKV 6144
#define NHEADS 32
#define HDIM 64
// log2(10000)/32
#define ROPE_L2 0.4152410118609203f

__device__ __forceinline__ void async_copy16(const bf16* g, bf16* l) {
  __builtin_amdgcn_global_load_lds(
      (const __attribute__((address_space(1))) void*)g,
      (__attribute__((address_space(3))) void*)l, 16, 0, 0);
}

__device__ __forceinline__ f32x4 mfma_bf16(short8 a, short8 b, f32x4 c) {
  return __builtin_amdgcn_mfma_f32_16x16x32_bf16(a, b, c, 0, 0, 0);
}

// ---------------- fused fp32 -> bf16 convert of x, Wqkv, Wo ----------------
__global__ __launch_bounds__(256) void cvt3_kernel(const float* __restrict__ sx,
                                                   bf16* __restrict__ dx,
                                                   const float* __restrict__ sw,
                                                   bf16* __restrict__ dw,
                                                   const float* __restrict__ so,
                                                   bf16* __restrict__ dov) {
  int i = blockIdx.x * 256 + threadIdx.x;
  const float* s;
  bf16* d;
  if (i < 1048576) {
    s = sx; d = dx;
  } else if (i < 4194304) {
    s = sw; d = dw; i -= 1048576;
  } else {
    s = so; d = dov; i -= 4194304;
  }
  const float4 v = ((const float4*)s)[i];
  union { bf16 h[4]; ushort4 u; } tmp;
  tmp.h[0] = __float2bfloat16(v.x);
  tmp.h[1] = __float2bfloat16(v.y);
  tmp.h[2] = __float2bfloat16(v.z);
  tmp.h[3] = __float2bfloat16(v.w);
  ((ushort4*)d)[i] = tmp.u;
}

// ---------------- GEMM1: qkv = x @ Wqkv^T, fused RoPE epilogue ----------------
// Proven R7 structure: BK=32, 16 KB LDS, measured-clean XOR swizzle.
__global__ __launch_bounds__(256) void gemm_qkv(const bf16* __restrict__ A,
                                                const bf16* __restrict__ W,
                                                bf16* __restrict__ q_ws,
                                                bf16* __restrict__ k_ws,
                                                bf16* __restrict__ v_ws) {
  constexpr int K = DMODEL;
  __shared__ bf16 smem[8192];          // As = smem[0:4096], Ws = smem[4096:8192]
  const int tid = threadIdx.x;
  const int wave = tid >> 6, lane = tid & 63;
  const int wm = wave >> 1, wn = wave & 1;
  const int m0 = blockIdx.y * 128, n0 = blockIdx.x * 128;
  const int sr = wave * 16 + (lane >> 2);
  const int swc = (((lane & 3) ^ ((lane >> 3) & 3)) * 8);  // swizzled src chunk
  const int fr = lane & 15, fq = lane >> 4;
  const int rdc = ((fq ^ ((fr >> 1) & 3)) * 8);

  const f32x4 zero = {0.f, 0.f, 0.f, 0.f};
  f32x4 acc[4][4];
  for (int i = 0; i < 4; ++i)
    for (int j = 0; j < 4; ++j) acc[i][j] = zero;

  for (int kt = 0; kt < K; kt += 32) {
    __syncthreads();
    for (int i2 = 0; i2 < 2; ++i2) {
      async_copy16(A + (size_t)(m0 + i2 * 64 + sr) * K + kt + swc,
                   &smem[(i2 * 64 + wave * 16) * 32]);
      async_copy16(W + (size_t)(n0 + i2 * 64 + sr) * K + kt + swc,
                   &smem[4096 + (i2 * 64 + wave * 16) * 32]);
    }
    __syncthreads();
    short8 a[4], b[4];
    for (int i = 0; i < 4; ++i)
      a[i] = *(const short8*)&smem[(wm * 64 + i * 16 + fr) * 32 + rdc];
    for (int j = 0; j < 4; ++j)
      b[j] = *(const short8*)&smem[4096 + (wn * 64 + j * 16 + fr) * 32 + rdc];
    for (int i = 0; i < 4; ++i)
      for (int j = 0; j < 4; ++j)
        acc[i][j] = mfma_bf16(a[i], b[j], acc[i][j]);
  }

  const int colb = n0 + wn * 64;
  const int sect = colb >> 11;          // 0=q, 1=k, 2=v (block-uniform)
  const int h = (colb & 2047) >> 6;
  const int col = fr, rq = fq * 4;

  if (sect < 2) {
    bf16* dst = ((sect == 0) ? q_ws : k_ws) + (size_t)h * S_LEN * HDIM;
    bf16* rep = smem + wave * 1152;     // 16 rows x stride 72 (16B-aligned)
    const float f0 = exp2f(-(float)col * ROPE_L2);
    const float f1 = exp2f(-(float)(16 + col) * ROPE_L2);
    __syncthreads();
    for (int i = 0; i < 4; ++i) {
      const int base_s = m0 + wm * 64 + i * 16;
#pragma unroll
      for (int jl = 0; jl < 2; ++jl) {
        const int dh = jl * 16 + col;
        const float fr_ = (jl == 0) ? f0 : f1;
#pragma unroll
        for (int r = 0; r < 4; ++r) {
          const int srow = base_s + rq + r;
          float sn, cs;
          __sincosf((float)srow * fr_, &sn, &cs);
          const float xl = acc[i][jl][r], xh = acc[i][jl + 2][r];
          rep[(rq + r) * 72 + dh]      = __float2bfloat16(xl * cs - xh * sn);
          rep[(rq + r) * 72 + dh + 32] = __float2bfloat16(xh * cs + xl * sn);
        }
      }
#pragma unroll
      for (int p = 0; p < 2; ++p) {
        const int rr = p * 8 + (lane >> 3), ch = lane & 7;
        const uint4 vv = *(const uint4*)&rep[rr * 72 + ch * 8];
        *(uint4*)&dst[(size_t)(base_s + rr) * HDIM + ch * 8] = vv;
      }
    }
  } else {
    // V stored transposed: [h][dh][s]
    bf16* dst = v_ws + (size_t)h * HDIM * S_LEN;
    for (int j = 0; j < 4; ++j) {
      const int dh = j * 16 + col;
      for (int i = 0; i < 4; ++i) {
        const int s0 = m0 + wm * 64 + i * 16 + rq;
        union { bf16 hx[4]; uint2 u; } vk;
#pragma unroll
        for (int r = 0; r < 4; ++r) vk.hx[r] = __float2bfloat16(acc[i][j][r]);
        *(uint2*)&dst[(size_t)dh * S_LEN + s0] = vk.u;
      }
    }
  }
}

// ---------------- flash attention (causal) — proven R5/R7 structure ----------------
// 256-thread blocks, grid 1024 = (qt LPT heavy-first) x 32 heads. 4 waves share
// K/V tiles double-buffered in LDS (global_load_lds w16, one barrier per k-tile).
// XOR chunk swizzle on staging. Transposed tile math: S^T = K·Q^T; O^T = V^T·P^T.
__global__ __launch_bounds__(256) void attn_kernel(const bf16* __restrict__ q_ws,
                                                   const bf16* __restrict__ k_ws,
                                                   const bf16* __restrict__ vt_ws,
                                                   bf16* __restrict__ attn_out) {
  const int bid = blockIdx.x;
  const int qt = 31 - (bid >> 5);      // heavy q-tiles first (LPT)
  const int h = bid & 31;

  const int tid = threadIdx.x, wave = tid >> 6, lane = tid & 63;
  const int col = lane & 15, fq = lane >> 4;
  const int q_glob = qt * 64 + wave * 16 + col;

  __shared__ bf16 Ks[2][64 * 64];
  __shared__ bf16 Vs[2][64 * 64];
  __shared__ bf16 Pl[4][16 * 72];
  bf16* pl = Pl[wave];

  const bf16* qh = q_ws + (size_t)h * S_LEN * HDIM;
  const bf16* kh = k_ws + (size_t)h * S_LEN * HDIM;
  const bf16* vh = vt_ws + (size_t)h * HDIM * S_LEN;

  const int srow = lane >> 3;
  const int slot = lane & 7;
  const int schunk = slot ^ srow;

  auto stage = [&](int kt, int buf) {
    const int k0 = kt * 64;
#pragma unroll
    for (int j = 0; j < 2; ++j) {
      const int r8 = (wave * 2 + j) * 8;
      async_copy16(kh + (size_t)(k0 + r8 + srow) * HDIM + schunk * 8,
                   &Ks[buf][r8 * 64]);
      async_copy16(vh + (size_t)(r8 + srow) * S_LEN + k0 + schunk * 8,
                   &Vs[buf][r8 * 64]);
    }
  };

  short8 qf[2];
#pragma unroll
  for (int ks = 0; ks < 2; ++ks)
    qf[ks] = *(const short8*)&qh[(size_t)q_glob * HDIM + ks * 32 + fq * 8];

  const f32x4 zero = {0.f, 0.f, 0.f, 0.f};
  f32x4 o_acc[4] = {zero, zero, zero, zero};
  float m_i = -1e30f, l_i = 0.f;

  stage(0, 0);

  for (int kt = 0; kt <= qt; ++kt) {
    const int buf = kt & 1;
    const int k0 = kt * 64;
    __syncthreads();
    if (kt < qt) stage(kt + 1, buf ^ 1);

    short8 kf[8];
#pragma unroll
    for (int n = 0; n < 4; ++n) {
      const int row = n * 16 + col;
#pragma unroll
      for (int ks = 0; ks < 2; ++ks)
        kf[n * 2 + ks] =
            *(const short8*)&Ks[buf][row * 64 + (((ks * 4 + fq) ^ (row & 7)) * 8)];
    }
    f32x4 s_acc[4] = {zero, zero, zero, zero};
#pragma unroll
    for (int n = 0; n < 4; ++n)
#pragma unroll
      for (int ks = 0; ks < 2; ++ks)
        s_acc[n] = mfma_bf16(kf[n * 2 + ks], qf[ks], s_acc[n]);

    short8 vf[8];
#pragma unroll
    for (int n = 0; n < 4; ++n) {
      const int row = n * 16 + col;
#pragma unroll
      for (int ks = 0; ks < 2; ++ks)
        vf[n * 2 + ks] =
            *(const short8*)&Vs[buf][row * 64 + (((ks * 4 + fq) ^ (row & 7)) * 8)];
    }

    if (kt == qt) {
#pragma unroll
      for (int n = 0; n < 4; ++n)
#pragma unroll
        for (int r = 0; r < 4; ++r)
          if (k0 + n * 16 + fq * 4 + r > q_glob) s_acc[n][r] = -1e30f;
    }

    float vmax = -1e30f;
#pragma unroll
    for (int n = 0; n < 4; ++n)
#pragma unroll
      for (int r = 0; r < 4; ++r) vmax = fmaxf(vmax, s_acc[n][r]);
    vmax = fmaxf(vmax, __shfl_xor(vmax, 16, 64));
    vmax = fmaxf(vmax, __shfl_xor(vmax, 32, 64));
    const float mnew = fmaxf(m_i, vmax);
    const float alpha = __expf((m_i - mnew) * 0.125f);
    m_i = mnew;

    float rs = 0.f;
#pragma unroll
    for (int n = 0; n < 4; ++n)
#pragma unroll
      for (int r = 0; r < 4; ++r) {
        const float p = __expf((s_acc[n][r] - mnew) * 0.125f);
        s_acc[n][r] = p;
        rs += p;
      }
    rs += __shfl_xor(rs, 16, 64);
    rs += __shfl_xor(rs, 32, 64);
    l_i = l_i * alpha + rs;

#pragma unroll
    for (int n = 0; n < 4; ++n)
#pragma unroll
      for (int r = 0; r < 4; ++r) o_acc[n][r] *= alpha;

#pragma unroll
    for (int n = 0; n < 4; ++n) {
      union { bf16 hx[4]; uint2 u; } pk;
#pragma unroll
      for (int r = 0; r < 4; ++r) pk.hx[r] = __float2bfloat16(s_acc[n][r]);
      *(uint2*)&pl[col * 72 + n * 16 + fq * 4] = pk.u;
    }
    short8 pa[2];
#pragma unroll
    for (int ks = 0; ks < 2; ++ks)
      pa[ks] = *(const short8*)&pl[col * 72 + ks * 32 + fq * 8];

#pragma unroll
    for (int n = 0; n < 4; ++n)
#pragma unroll
      for (int ks = 0; ks < 2; ++ks)
        o_acc[n] = mfma_bf16(vf[n * 2 + ks], pa[ks], o_acc[n]);
  }

  const float inv = 1.0f / l_i;
#pragma unroll
  for (int n = 0; n < 4; ++n) {
#pragma unroll
    for (int r = 0; r < 4; ++r) o_acc[n][r] *= inv;
    union { bf16 hx[4]; uint2 u; } ok;
#pragma unroll
    for (int r = 0; r < 4; ++r) ok.hx[r] = __float2bfloat16(o_acc[n][r]);
    *(uint2*)&attn_out[(size_t)q_glob * DMODEL + h * HDIM + n * 16 + fq * 4] = ok.u;
  }
}

// ---------------- GEMM2: out = attn @ Wo^T, fused residual+gate ----------------
// 64x128 tile, BK=32, EIGHT waves (512 thr): wave = 16 rows x 64 cols
// (wm=wave>>1, wn=wave&1). Grid 512 = 2 blocks/CU -> 16 waves/CU to hide
// barrier/vmcnt drains. Staging: every wave stages 16 B-rows; waves 0-3 also
// stage 16 A-rows (proven 16-rows-per-issue geometry + clean swizzle).
__global__ __launch_bounds__(512) void gemm_out(const bf16* __restrict__ A,
                                                const bf16* __restrict__ W,
                                                const float* __restrict__ xres,
                                                const float* __restrict__ gate,
                                                float* __restrict__ out) {
  constexpr int K = DMODEL;
  __shared__ bf16 As[64 * 32];
  __shared__ bf16 Bs[128 * 32];
  const int tid = threadIdx.x;
  const int wave = tid >> 6, lane = tid & 63;
  const int wm = wave >> 1, wn = wave & 1;
  const int m0 = blockIdx.y * 64, n0 = blockIdx.x * 128;
  const int sr = lane >> 2;
  const int swc = (((lane & 3) ^ ((lane >> 3) & 3)) * 8);
  const int fr = lane & 15, fq = lane >> 4;
  const int rdc = ((fq ^ ((fr >> 1) & 3)) * 8);

  const f32x4 zero = {0.f, 0.f, 0.f, 0.f};
  f32x4 acc[4];
  for (int j = 0; j < 4; ++j) acc[j] = zero;

  for (int kt = 0; kt < K; kt += 32) {
    __syncthreads();
    async_copy16(W + (size_t)(n0 + wave * 16 + sr) * K + kt + swc,
                 &Bs[(wave * 16) * 32]);
    if (wave < 4)
      async_copy16(A + (size_t)(m0 + wave * 16 + sr) * K + kt + swc,
                   &As[(wave * 16) * 32]);
    __syncthreads();
    short8 a, b[4];
    a = *(const short8*)&As[(wm * 16 + fr) * 32 + rdc];
    for (int j = 0; j < 4; ++j)
      b[j] = *(const short8*)&Bs[(wn * 64 + j * 16 + fr) * 32 + rdc];
    for (int j = 0; j < 4; ++j)
      acc[j] = mfma_bf16(a, b[j], acc[j]);
  }

  const int col = fr, rq = fq * 4;
  for (int j = 0; j < 4; ++j) {
    const int cc = n0 + wn * 64 + j * 16 + col;
    const float g = gate[cc];
    const int base_row = m0 + wm * 16 + rq;
    for (int r = 0; r < 4; ++r) {
      const size_t idx = (size_t)(base_row + r) * DMODEL + cc;
      out[idx] = xres[idx] + g * acc[j][r];
    }
  }
}

extern "C" void kernel_launch(void* const* d_in, const int* in_sizes, int n_in,
                              void* d_out, int out_size, void* d_ws, size_t ws_size,
                              hipStream_t stream) {
  const float* x    = (const float*)d_in[0];
  const float* Wqkv = (const float*)d_in[1];
  const float* Wo   = (const float*)d_in[2];
  const float* gate = (const float*)d_in[3];
  float* out = (float*)d_out;

  char* ws = (char*)d_ws;
  const size_t MB = 1024 * 1024;
  bf16* xb      = (bf16*)(ws);                 // 8 MB   (dead after gemm_qkv)
  bf16* wqkvb   = (bf16*)(ws + 8 * MB);        // 24 MB  (dead after gemm_qkv)
  bf16* wob     = (bf16*)(ws + 32 * MB);       // 8 MB
  bf16* q_ws    = (bf16*)(ws + 40 * MB);       // 8 MB  [h][s][dh]
  bf16* k_ws    = (bf16*)(ws + 48 * MB);       // 8 MB  [h][s][dh]
  bf16* v_ws    = (bf16*)(ws + 56 * MB);       // 8 MB  [h][dh][s] (pre-transposed)
  bf16* attn_ws = (bf16*)(ws);                 // aliases xb

  cvt3_kernel<<<dim3(20480), 256, 0, stream>>>(x, xb, Wqkv, wqkvb, Wo, wob);

  gemm_qkv<<<dim3(NQKV / 128, DMODEL / 128), 256, 0, stream>>>(xb, wqkvb, q_ws, k_ws, v_ws);
  attn_kernel<<<dim3(1024), 256, 0, stream>>>(q_ws, k_ws, v_ws, attn_ws);
  gemm_out<<<dim3(DMODEL / 128, DMODEL / 64), 512, 0, stream>>>(attn_ws, wob, x, gate, out);
}